// Round 1
// baseline (165.540 us; speedup 1.0000x reference)
//
#include <hip/hip_runtime.h>

#define NT 512            // threads per block (8 waves)
#define NB 2              // batches per block
#define NPOS 1024         // positions (tree leaves) per batch
#define CH 8              // channels

struct WPtrs {
  const float* W[10];
  const float* Bv[10];
};

// XOR-swizzle on 16B-chunk index: spreads strided chunk accesses across bank groups.
__device__ __forceinline__ int swz(int ci) { return ci ^ ((ci >> 3) & 7); }

__global__ __launch_bounds__(NT, 2) void butterfly_kernel(
    const float* __restrict__ x,
    const float* __restrict__ F,      // in_filter [16][1][8]
    const float* __restrict__ fbias,  // [8]
    WPtrs P,
    const float* __restrict__ fea,    // [1024][8][16]
    float* __restrict__ out)
{
  // state: per batch, 1024 rows x 8ch fp32 = 2048 float4 chunks. Ping-pong.
  __shared__ float4 sA[NB * 2048];
  __shared__ float4 sB[NB * 2048];

  const int tid = threadIdx.x;
  const int b0 = blockIdx.x * NB;

  // ---------------- phase 1: input conv (kernel=16, stride=16) ----------------
  // v[n][c] = relu(sum_f x[b, n*16+f] * F[f*8+c] + fbias[c]);  row n -> chunks 2n,2n+1
  float Fw[128];
  {
    const float4* F4 = (const float4*)F;
#pragma unroll
    for (int i = 0; i < 32; ++i) {
      float4 v = F4[i];
      Fw[4*i+0] = v.x; Fw[4*i+1] = v.y; Fw[4*i+2] = v.z; Fw[4*i+3] = v.w;
    }
  }
  float ib[8];
  {
    const float4* B4 = (const float4*)fbias;
    float4 v0 = B4[0], v1 = B4[1];
    ib[0]=v0.x; ib[1]=v0.y; ib[2]=v0.z; ib[3]=v0.w;
    ib[4]=v1.x; ib[5]=v1.y; ib[6]=v1.z; ib[7]=v1.w;
  }
#pragma unroll
  for (int i = 0; i < (NB * NPOS) / NT; ++i) {   // 4 iterations
    int item = tid + i * NT;
    int nb = item >> 10;
    int n  = item & 1023;
    const float4* xb = (const float4*)(x + ((size_t)(b0 + nb)) * 16384 + n * 16);
    float xin[16];
#pragma unroll
    for (int q = 0; q < 4; ++q) {
      float4 v = xb[q];
      xin[4*q+0] = v.x; xin[4*q+1] = v.y; xin[4*q+2] = v.z; xin[4*q+3] = v.w;
    }
    float acc[8];
#pragma unroll
    for (int c = 0; c < 8; ++c) acc[c] = ib[c];
#pragma unroll
    for (int f = 0; f < 16; ++f) {
#pragma unroll
      for (int c = 0; c < 8; ++c) acc[c] += xin[f] * Fw[f * 8 + c];
    }
    float4 r0 = make_float4(fmaxf(acc[0],0.f), fmaxf(acc[1],0.f), fmaxf(acc[2],0.f), fmaxf(acc[3],0.f));
    float4 r1 = make_float4(fmaxf(acc[4],0.f), fmaxf(acc[5],0.f), fmaxf(acc[6],0.f), fmaxf(acc[7],0.f));
    sA[nb * 2048 + swz(2*n)]     = r0;
    sA[nb * 2048 + swz(2*n + 1)] = r1;
  }
  __syncthreads();

  // ---------------- phase 2: 10 butterfly levels ----------------
  // Level lvl (0-based) computes children count K = 2^(lvl+1) using W_{lvl+1}.
  // Flat layout p = t*K + k. Child row r = t*K + k reads parent rows
  // q0 = t*K + (k>>1), q1 = q0 + K/2 from SAME aligned block (t-major locality).
  float4* src = sA;
  float4* dst = sB;
  for (int lvl = 0; lvl < 10; ++lvl) {
    const int K   = 2 << lvl;
    const int T   = NPOS / K;
    const int lgT = 9 - lvl;
    const float* Wl = P.W[lvl];   // [K][2][8][8]
    const float* Bl = P.Bv[lvl];  // [K][8]
    int kStart, kStep, jStart, jStep;
    if (K >= NT) { kStart = tid; kStep = NT; jStart = 0; jStep = 1; }
    else {
      int tpp = NT / K;                 // threads sharing one branch k
      kStart = tid / tpp; kStep = K;    // single k iteration
      jStart = tid - kStart * tpp; jStep = tpp;
    }
    const int NBT = NB * T;
    for (int k = kStart; k < K; k += kStep) {
      // load this branch's 128 weights + 8 bias into registers (read once per block)
      float w[128];
      {
        const float4* W4 = (const float4*)(Wl + k * 128);
#pragma unroll
        for (int i2 = 0; i2 < 32; ++i2) {
          float4 v = W4[i2];
          w[4*i2+0] = v.x; w[4*i2+1] = v.y; w[4*i2+2] = v.z; w[4*i2+3] = v.w;
        }
      }
      float bk[8];
      {
        const float4* B4 = (const float4*)(Bl + k * 8);
        float4 v0 = B4[0], v1 = B4[1];
        bk[0]=v0.x; bk[1]=v0.y; bk[2]=v0.z; bk[3]=v0.w;
        bk[4]=v1.x; bk[5]=v1.y; bk[6]=v1.z; bk[7]=v1.w;
      }
      const int kp = k >> 1;
      for (int j = jStart; j < NBT; j += jStep) {
        int t  = j & (T - 1);
        int nb = j >> lgT;
        const float4* s = src + nb * 2048;
        float4*       dd = dst + nb * 2048;
        int q0 = t * K + kp;
        int q1 = q0 + (K >> 1);
        float4 a0 = s[swz(2*q0)],  a1 = s[swz(2*q0 + 1)];
        float4 c0 = s[swz(2*q1)],  c1 = s[swz(2*q1 + 1)];
        float pa[8] = {a0.x,a0.y,a0.z,a0.w,a1.x,a1.y,a1.z,a1.w};
        float pb[8] = {c0.x,c0.y,c0.z,c0.w,c1.x,c1.y,c1.z,c1.w};
        float acc[8];
#pragma unroll
        for (int d = 0; d < 8; ++d) acc[d] = bk[d];
#pragma unroll
        for (int c = 0; c < 8; ++c) {
#pragma unroll
          for (int d = 0; d < 8; ++d)
            acc[d] += pa[c] * w[c * 8 + d] + pb[c] * w[64 + c * 8 + d];
        }
        int r = t * K + k;
        float4 o0 = make_float4(fmaxf(acc[0],0.f), fmaxf(acc[1],0.f), fmaxf(acc[2],0.f), fmaxf(acc[3],0.f));
        float4 o1 = make_float4(fmaxf(acc[4],0.f), fmaxf(acc[5],0.f), fmaxf(acc[6],0.f), fmaxf(acc[7],0.f));
        dd[swz(2*r)]     = o0;
        dd[swz(2*r + 1)] = o1;
      }
    }
    __syncthreads();
    float4* tmp = src; src = dst; dst = tmp;
  }

  // ---------------- phase 3: per-branch dense [8 -> 16] ----------------
  // out[b, k*16+f] = sum_c state[k][c] * fea[k*128 + c*16 + f]
#pragma unroll 1
  for (int i = 0; i < 16384 / NT; ++i) {   // 32 iterations over (k,f)
    int o = tid + i * NT;
    int k = o >> 4, f = o & 15;
    float fd[8];
#pragma unroll
    for (int c = 0; c < 8; ++c) fd[c] = fea[k * 128 + c * 16 + f];
#pragma unroll
    for (int nb = 0; nb < NB; ++nb) {
      float4 s0 = src[nb * 2048 + swz(2*k)];
      float4 s1 = src[nb * 2048 + swz(2*k + 1)];
      float acc = s0.x*fd[0] + s0.y*fd[1] + s0.z*fd[2] + s0.w*fd[3]
                + s1.x*fd[4] + s1.y*fd[5] + s1.z*fd[6] + s1.w*fd[7];
      out[((size_t)(b0 + nb)) * 16384 + o] = acc;
    }
  }
}

extern "C" void kernel_launch(void* const* d_in, const int* in_sizes, int n_in,
                              void* d_out, int out_size, void* d_ws, size_t ws_size,
                              hipStream_t stream) {
  const float* x  = (const float*)d_in[0];
  const float* F  = (const float*)d_in[1];
  const float* fb = (const float*)d_in[2];
  WPtrs P;
  for (int l = 0; l < 10; ++l) {
    P.W[l]  = (const float*)d_in[3 + 2 * l];
    P.Bv[l] = (const float*)d_in[4 + 2 * l];
  }
  const float* fea = (const float*)d_in[23];
  float* out = (float*)d_out;
  dim3 grid(1024 / NB), block(NT);
  butterfly_kernel<<<grid, block, 0, stream>>>(x, F, fb, P, fea, out);
}